// Round 6
// baseline (323.320 us; speedup 1.0000x reference)
//
#include <hip/hip_runtime.h>
#include <math.h>
#include <stdint.h>

#define D 128          // feature dim (d_in = d_h = 128)
#define SCAN_CHUNK 2048
#define LDA 136        // LDS row stride in shorts (+8 pad: 16-way -> 2-way bank conflict)

typedef __attribute__((ext_vector_type(8))) short v8s;   // 8 bf16 (4 VGPRs)
typedef __attribute__((ext_vector_type(4))) float v4f;   // MFMA accumulator

// bf16 round-to-nearest-even
static __device__ __forceinline__ uint16_t f2bf(float f) {
    uint32_t u = __float_as_uint(f);
    u = (u + 0x7fff + ((u >> 16) & 1)) >> 16;
    return (uint16_t)u;
}
static __device__ __forceinline__ float bf2f(uint16_t h) { return __uint_as_float((uint32_t)h << 16); }
static __device__ __forceinline__ float bf_lo(uint32_t u) { return __uint_as_float(u << 16); }
static __device__ __forceinline__ float bf_hi(uint32_t u) { return __uint_as_float(u & 0xffff0000u); }

// ---------------- count + W-pack (fused, independent work) ----------------
// pack layout: frag f = kstep*8 + tile (0..31); element ((f*64)+lane)*8 + j
// maps to W[k = kstep*32 + (lane>>4)*8 + j][nn = tile*16 + (lane&15)]

__global__ void countpack_kernel(const int* __restrict__ col, int* __restrict__ cnt, int E,
                                 const float* __restrict__ W1, const float* __restrict__ W2,
                                 uint16_t* __restrict__ Wh, uint16_t* __restrict__ Wl) {
    int tid = blockIdx.x * blockDim.x + threadIdx.x;
    if (tid < 2 * 16384) {
        int layer = tid >> 14;
        int li = tid & 16383;
        int j = li & 7, lane = (li >> 3) & 63, f = li >> 9;
        int kstep = f >> 3, tile = f & 7;
        int k = kstep * 32 + ((lane >> 4) * 8) + j;
        int nn = tile * 16 + (lane & 15);
        const float* W = layer ? W2 : W1;
        float v = W[k * 128 + nn];
        uint16_t h = f2bf(v);
        Wh[tid] = h;
        Wl[tid] = f2bf(v - bf2f(h));
    }
    if (tid < E) atomicAdd(&cnt[col[tid]], 1);
}

// ---------------- scan phase A: per-chunk sums (+ fused dinv) ----------------

__global__ __launch_bounds__(256) void scanA_kernel(const int* __restrict__ cnt,
                                                    int* __restrict__ bsum,
                                                    float* __restrict__ dinv, int n) {
    __shared__ int wsum[4];
    int b = blockIdx.x, t = threadIdx.x;
    int base = b * SCAN_CHUNK;
    int s = 0;
#pragma unroll
    for (int k = 0; k < SCAN_CHUNK / 256; k++) {
        int i = base + k * 256 + t;
        if (i < n) {
            int c = cnt[i];
            s += c;
            dinv[i] = rsqrtf((float)c + 1.0f);
        }
    }
#pragma unroll
    for (int off = 32; off > 0; off >>= 1) s += __shfl_xor(s, off, 64);
    if ((t & 63) == 0) wsum[t >> 6] = s;
    __syncthreads();
    if (t == 0) bsum[b] = wsum[0] + wsum[1] + wsum[2] + wsum[3];
}

// ---------------- scan phase C: local exclusive scan, block bases inlined ----------------

__global__ __launch_bounds__(256) void scanC_kernel(const int* __restrict__ cnt,
                                                    const int* __restrict__ bsum,
                                                    int* __restrict__ offs, int n, int nb) {
    __shared__ int stage[SCAN_CHUNK];
    __shared__ int res[SCAN_CHUNK];
    __shared__ int tsum[256];
    __shared__ int sb[64];
    int b = blockIdx.x, t = threadIdx.x;
    // first wave: inclusive scan of the (<=64) chunk sums
    if (t < 64) {
        int v = (t < nb) ? bsum[t] : 0;
        int inc = v;
#pragma unroll
        for (int off = 1; off < 64; off <<= 1) {
            int u = __shfl_up(inc, off, 64);
            if (t >= off) inc += u;
        }
        sb[t] = inc;
    }
    int base = b * SCAN_CHUNK;
#pragma unroll
    for (int k = 0; k < SCAN_CHUNK / 256; k++) {
        int i = base + k * 256 + t;
        stage[k * 256 + t] = (i < n) ? cnt[i] : 0;
    }
    __syncthreads();
    int my = 0;
#pragma unroll
    for (int j = 0; j < 8; j++) my += stage[t * 8 + j];
    tsum[t] = my;
    __syncthreads();
    for (int off = 1; off < 256; off <<= 1) {
        int v = (t >= off) ? tsum[t - off] : 0;
        __syncthreads();
        tsum[t] += v;
        __syncthreads();
    }
    int bbase = (b == 0) ? 0 : sb[b - 1];
    int run = tsum[t] - my + bbase;
#pragma unroll
    for (int j = 0; j < 8; j++) {
        res[t * 8 + j] = run;
        run += stage[t * 8 + j];
    }
    __syncthreads();
#pragma unroll
    for (int k = 0; k < SCAN_CHUNK / 256; k++) {
        int i = base + k * 256 + t;
        if (i < n) offs[i] = res[k * 256 + t];
    }
    if (b == gridDim.x - 1 && t == 0) offs[n] = sb[nb - 1];
}

__global__ void fill_kernel(const int* row, const int* col, const int* offs,
                            int* curs, int* adj, int E) {
    int e = blockIdx.x * blockDim.x + threadIdx.x;
    if (e < E) {
        int c = col[e];
        int p = atomicAdd(&curs[c], 1);
        adj[offs[c] + p] = row[e];
    }
}

// ---------------- MFMA GEMM: xwb[i,:] = bf16( dinv[i] * (A[i,:] @ W) ) ----------------
// split-bf16 (Markidis): A = Ah + Al, W = Wh + Wl; A@W ≈ Ah@Wh + Ah@Wl + Al@Wh

__global__ __launch_bounds__(256) void gemm_mfma_kernel(const float* __restrict__ A,
                                                        const uint16_t* __restrict__ Wph,
                                                        const uint16_t* __restrict__ Wpl,
                                                        const float* __restrict__ dinv,
                                                        uint16_t* __restrict__ Cb, int M) {
    __shared__ uint16_t Ah[64][LDA];
    __shared__ uint16_t Al[64][LDA];
    int t = threadIdx.x;
    int base_row = blockIdx.x * 64;

#pragma unroll
    for (int kk = 0; kk < 8; kk++) {
        int idx = kk * 256 + t;
        int r = idx >> 5;
        int c4 = idx & 31;
        int gr = base_row + r;
        float4 f = (gr < M) ? *(const float4*)(A + (size_t)gr * D + c4 * 4)
                            : make_float4(0.f, 0.f, 0.f, 0.f);
        uint16_t h0 = f2bf(f.x), h1 = f2bf(f.y), h2 = f2bf(f.z), h3 = f2bf(f.w);
        uint16_t l0 = f2bf(f.x - bf2f(h0)), l1 = f2bf(f.y - bf2f(h1));
        uint16_t l2 = f2bf(f.z - bf2f(h2)), l3 = f2bf(f.w - bf2f(h3));
        *(ushort4*)&Ah[r][c4 * 4] = make_ushort4(h0, h1, h2, h3);
        *(ushort4*)&Al[r][c4 * 4] = make_ushort4(l0, l1, l2, l3);
    }
    __syncthreads();

    int lane = t & 63, w = t >> 6;
    int m_l = lane & 15, quad = lane >> 4;
    int arow = w * 16 + m_l;

    v4f acc[8];
#pragma unroll
    for (int i = 0; i < 8; i++) acc[i] = (v4f){0.f, 0.f, 0.f, 0.f};

#pragma unroll
    for (int ks = 0; ks < 4; ks++) {
        v8s ah = *(const v8s*)&Ah[arow][ks * 32 + quad * 8];
        v8s al = *(const v8s*)&Al[arow][ks * 32 + quad * 8];
#pragma unroll
        for (int ti = 0; ti < 8; ti++) {
            int f = ks * 8 + ti;
            v8s bh = *(const v8s*)(Wph + ((size_t)(f * 64 + lane)) * 8);
            v8s bl = *(const v8s*)(Wpl + ((size_t)(f * 64 + lane)) * 8);
            acc[ti] = __builtin_amdgcn_mfma_f32_16x16x32_bf16(al, bh, acc[ti], 0, 0, 0);
            acc[ti] = __builtin_amdgcn_mfma_f32_16x16x32_bf16(ah, bl, acc[ti], 0, 0, 0);
            acc[ti] = __builtin_amdgcn_mfma_f32_16x16x32_bf16(ah, bh, acc[ti], 0, 0, 0);
        }
    }

    int rbase = base_row + w * 16 + quad * 4;
#pragma unroll
    for (int reg = 0; reg < 4; reg++) {
        int gr = rbase + reg;
        if (gr < M) {
            float di = dinv[gr];
#pragma unroll
            for (int ti = 0; ti < 8; ti++) {
                Cb[(size_t)gr * D + ti * 16 + m_l] = f2bf(di * acc[ti][reg]);
            }
        }
    }
}

// ---------------- aggregation (shared gather core) ----------------
// one wave per node; 16 lanes per row (uint4 = 8 bf16), 4 virtual edges in flight.
// virtual edge 0 = self row; edges 1..deg = adj[s..e).

#define AGG_GATHER(ACC_STMT)                                                     \
    int s = offs[i], e = offs[i + 1];                                            \
    int total = e - s + 1;                                                       \
    float a0=0,a1=0,a2=0,a3=0,a4=0,a5=0,a6=0,a7=0;                               \
    const uint4* xw4 = (const uint4*)xwb;                                        \
    int vt = 0;                                                                  \
    for (; vt + 8 <= total; vt += 8) {                                           \
        int m0 = vt + q, m1 = vt + 4 + q;                                        \
        int r0 = (m0 > 0) ? adj[s + m0 - 1] : i;                                 \
        int r1 = adj[s + m1 - 1];                                                \
        uint4 u0 = xw4[(size_t)r0 * 16 + sl];                                    \
        uint4 u1 = xw4[(size_t)r1 * 16 + sl];                                    \
        { uint4 u = u0; ACC_STMT }                                               \
        { uint4 u = u1; ACC_STMT }                                               \
    }                                                                            \
    for (; vt < total; vt += 4) {                                                \
        int myv = vt + q;                                                        \
        bool valid = myv < total;                                                \
        int r = i;                                                               \
        if (valid && myv > 0) r = adj[s + myv - 1];                              \
        uint4 u = xw4[(size_t)r * 16 + sl];                                      \
        if (valid) { ACC_STMT }                                                  \
    }                                                                            \
    a0 += __shfl_xor(a0, 16, 64); a1 += __shfl_xor(a1, 16, 64);                  \
    a2 += __shfl_xor(a2, 16, 64); a3 += __shfl_xor(a3, 16, 64);                  \
    a4 += __shfl_xor(a4, 16, 64); a5 += __shfl_xor(a5, 16, 64);                  \
    a6 += __shfl_xor(a6, 16, 64); a7 += __shfl_xor(a7, 16, 64);                  \
    a0 += __shfl_xor(a0, 32, 64); a1 += __shfl_xor(a1, 32, 64);                  \
    a2 += __shfl_xor(a2, 32, 64); a3 += __shfl_xor(a3, 32, 64);                  \
    a4 += __shfl_xor(a4, 32, 64); a5 += __shfl_xor(a5, 32, 64);                  \
    a6 += __shfl_xor(a6, 32, 64); a7 += __shfl_xor(a7, 32, 64);

#define ACC8 \
    a0 += bf_lo(u.x); a1 += bf_hi(u.x); a2 += bf_lo(u.y); a3 += bf_hi(u.y); \
    a4 += bf_lo(u.z); a5 += bf_hi(u.z); a6 += bf_lo(u.w); a7 += bf_hi(u.w);

// layer-1: write h (fp32)
__global__ __launch_bounds__(256) void agg1_kernel(const uint32_t* __restrict__ xwb,
                                                   const int* __restrict__ adj,
                                                   const int* __restrict__ offs,
                                                   const float* __restrict__ dinv,
                                                   const float* __restrict__ bias,
                                                   float* __restrict__ hout, int n) {
    int wave = (int)((blockIdx.x * (size_t)blockDim.x + threadIdx.x) >> 6);
    if (wave >= n) return;
    int lane = threadIdx.x & 63;
    int q = lane >> 4, sl = lane & 15;
    int i = wave;
    AGG_GATHER(ACC8)
    if (q == 0) {
        float di = dinv[i];
        float4 b0 = ((const float4*)bias)[2 * sl];
        float4 b1 = ((const float4*)bias)[2 * sl + 1];
        float4 o0, o1;
        o0.x = fmaxf(fmaf(di, a0, b0.x), 0.f);
        o0.y = fmaxf(fmaf(di, a1, b0.y), 0.f);
        o0.z = fmaxf(fmaf(di, a2, b0.z), 0.f);
        o0.w = fmaxf(fmaf(di, a3, b0.w), 0.f);
        o1.x = fmaxf(fmaf(di, a4, b1.x), 0.f);
        o1.y = fmaxf(fmaf(di, a5, b1.y), 0.f);
        o1.z = fmaxf(fmaf(di, a6, b1.z), 0.f);
        o1.w = fmaxf(fmaf(di, a7, b1.w), 0.f);
        ((float4*)(hout + (size_t)i * D))[2 * sl] = o0;
        ((float4*)(hout + (size_t)i * D))[2 * sl + 1] = o1;
    }
}

// layer-2 fused with edge-classifier precompute: emit P1/P2 directly, never write h.
__global__ __launch_bounds__(256) void agg2pq_kernel(const uint32_t* __restrict__ xwb,
                                                     const int* __restrict__ adj,
                                                     const int* __restrict__ offs,
                                                     const float* __restrict__ dinv,
                                                     const float* __restrict__ bias,
                                                     const float* __restrict__ Wfc,
                                                     const float* __restrict__ bfc,
                                                     float* __restrict__ P1,
                                                     float* __restrict__ P2, int n) {
    int wave = (int)((blockIdx.x * (size_t)blockDim.x + threadIdx.x) >> 6);
    if (wave >= n) return;
    int lane = threadIdx.x & 63;
    int q = lane >> 4, sl = lane & 15;
    int i = wave;
    AGG_GATHER(ACC8)
    // all 64 lanes now hold identical per-sl sums (duplicated over q)
    float di = dinv[i];
    float4 b0 = ((const float4*)bias)[2 * sl];
    float4 b1 = ((const float4*)bias)[2 * sl + 1];
    float o[8];
    o[0] = fmaxf(fmaf(di, a0, b0.x), 0.f);
    o[1] = fmaxf(fmaf(di, a1, b0.y), 0.f);
    o[2] = fmaxf(fmaf(di, a2, b0.z), 0.f);
    o[3] = fmaxf(fmaf(di, a3, b0.w), 0.f);
    o[4] = fmaxf(fmaf(di, a4, b1.x), 0.f);
    o[5] = fmaxf(fmaf(di, a5, b1.y), 0.f);
    o[6] = fmaxf(fmaf(di, a6, b1.z), 0.f);
    o[7] = fmaxf(fmaf(di, a7, b1.w), 0.f);
    float p[8] = {0.f, 0.f, 0.f, 0.f, 0.f, 0.f, 0.f, 0.f};
    const float4* W4 = (const float4*)Wfc;   // [256][4]
#pragma unroll
    for (int tt = 0; tt < 8; tt++) {
        int f = 8 * sl + tt;
        float4 w1 = W4[f];
        float4 w2 = W4[128 + f];
        p[0] = fmaf(o[tt], w1.x, p[0]); p[1] = fmaf(o[tt], w1.y, p[1]);
        p[2] = fmaf(o[tt], w1.z, p[2]); p[3] = fmaf(o[tt], w1.w, p[3]);
        p[4] = fmaf(o[tt], w2.x, p[4]); p[5] = fmaf(o[tt], w2.y, p[5]);
        p[6] = fmaf(o[tt], w2.z, p[6]); p[7] = fmaf(o[tt], w2.w, p[7]);
    }
#pragma unroll
    for (int off = 1; off < 64; off <<= 1) {
#pragma unroll
        for (int j = 0; j < 8; j++) p[j] += __shfl_xor(p[j], off, 64);
    }
    if (lane == 0) {
        // sums are 4x-duplicated (q quarters) -> exact 0.25 correction
        ((float4*)P1)[i] = make_float4(0.25f * p[0] + bfc[0], 0.25f * p[1] + bfc[1],
                                       0.25f * p[2] + bfc[2], 0.25f * p[3] + bfc[3]);
        ((float4*)P2)[i] = make_float4(0.25f * p[4], 0.25f * p[5], 0.25f * p[6], 0.25f * p[7]);
    }
}

// ---------------- edge classifier: one THREAD per edge ----------------

__global__ __launch_bounds__(256) void edge2_kernel(const int* __restrict__ row,
                                                    const int* __restrict__ col,
                                                    const float* __restrict__ P1,
                                                    const float* __restrict__ P2,
                                                    float* __restrict__ out, int E) {
    int e = blockIdx.x * blockDim.x + threadIdx.x;
    if (e >= E) return;
    int r = row[e], c = col[e];
    float4 a = ((const float4*)P1)[r];
    float4 b = ((const float4*)P2)[c];
    float sx = a.x + b.x, sy = a.y + b.y, sz = a.z + b.z, sw = a.w + b.w;
    float m = fmaxf(fmaxf(sx, sy), fmaxf(sz, sw));
    float e0 = expf(sx - m), e1 = expf(sy - m), e2 = expf(sz - m), e3 = expf(sw - m);
    float lse = m + logf(e0 + e1 + e2 + e3);
    *(float4*)(out + (size_t)e * 4) = make_float4(sx - lse, sy - lse, sz - lse, sw - lse);
}

// ---------------- launch ----------------

extern "C" void kernel_launch(void* const* d_in, const int* in_sizes, int n_in,
                              void* d_out, int out_size, void* d_ws, size_t ws_size,
                              hipStream_t stream) {
    const float* x   = (const float*)d_in[0];
    const int*   ei  = (const int*)d_in[1];
    const float* W1  = (const float*)d_in[2];
    const float* b1  = (const float*)d_in[3];
    const float* W2  = (const float*)d_in[4];
    const float* b2  = (const float*)d_in[5];
    const float* Wfc = (const float*)d_in[6];
    const float* bfc = (const float*)d_in[7];
    float* out = (float*)d_out;

    int n = in_sizes[0] / D;        // 50000
    int E = in_sizes[1] / 2;        // 600000
    const int* row = ei;            // edge_index[0]
    const int* col = ei + E;        // edge_index[1]

    int nbScan = (n + SCAN_CHUNK - 1) / SCAN_CHUNK;   // 25

    // workspace layout (all segments 16B-aligned)
    uint16_t* xwb  = (uint16_t*)d_ws;                    // n*D bf16 (dinv-prescaled xW)
    float*    h    = (float*)(xwb + (size_t)n * D);      // n*D f32 (layer-1 output only)
    int*      cnt  = (int*)(h + (size_t)n * D);          // n   } adjacent for one memset
    int*      curs = cnt + n;                            // n   }
    int*      offs = curs + n;                           // n+4 (padded for alignment)
    int*      bsum = offs + (n + 4);                     // 64
    int*      adj  = bsum + 64;                          // E
    float*    dinv = (float*)(adj + E);                  // n
    uint16_t* Wph  = (uint16_t*)(dinv + n);              // 2*16384 (layer-major)
    uint16_t* Wpl  = Wph + 2 * 16384;                    // 2*16384
    float*    P1   = (float*)(Wpl + 2 * 16384);          // n*4
    float*    P2   = P1 + (size_t)n * 4;                 // n*4

    int nb_e = (E + 255) / 256;

    // CSR build (+ W pack fused into count)
    hipMemsetAsync(cnt, 0, (size_t)2 * n * sizeof(int), stream);   // cnt + curs
    countpack_kernel<<<nb_e, 256, 0, stream>>>(col, cnt, E, W1, W2, Wph, Wpl);
    scanA_kernel<<<nbScan, 256, 0, stream>>>(cnt, bsum, dinv, n);
    scanC_kernel<<<nbScan, 256, 0, stream>>>(cnt, bsum, offs, n, nbScan);
    fill_kernel<<<nb_e, 256, 0, stream>>>(row, col, offs, curs, adj, E);

    int nbG = (n + 63) / 64;

    // layer 1
    gemm_mfma_kernel<<<nbG, 256, 0, stream>>>(x, Wph, Wpl, dinv, xwb, n);
    agg1_kernel<<<(n + 3) / 4, 256, 0, stream>>>((const uint32_t*)xwb, adj, offs, dinv, b1, h, n);
    // layer 2 (+ fused pq epilogue)
    gemm_mfma_kernel<<<nbG, 256, 0, stream>>>(h, Wph + 16384, Wpl + 16384, dinv, xwb, n);
    agg2pq_kernel<<<(n + 3) / 4, 256, 0, stream>>>((const uint32_t*)xwb, adj, offs, dinv, b2,
                                                   Wfc, bfc, P1, P2, n);
    // edge classifier
    edge2_kernel<<<nb_e, 256, 0, stream>>>(row, col, P1, P2, out, E);
}

// Round 7
// 260.202 us; speedup vs baseline: 1.2426x; 1.2426x over previous
//
#include <hip/hip_runtime.h>
#include <math.h>
#include <stdint.h>

#define D 128          // feature dim (d_in = d_h = 128)
#define SCAN_CHUNK 2048
#define LDA 136        // LDS row stride in shorts (+8 pad: 16-way -> 2-way bank conflict)

typedef __attribute__((ext_vector_type(8))) short v8s;   // 8 bf16 (4 VGPRs)
typedef __attribute__((ext_vector_type(4))) float v4f;   // MFMA accumulator

// bf16 round-to-nearest-even
static __device__ __forceinline__ uint16_t f2bf(float f) {
    uint32_t u = __float_as_uint(f);
    u = (u + 0x7fff + ((u >> 16) & 1)) >> 16;
    return (uint16_t)u;
}
static __device__ __forceinline__ float bf2f(uint16_t h) { return __uint_as_float((uint32_t)h << 16); }
static __device__ __forceinline__ float bf_lo(uint32_t u) { return __uint_as_float(u << 16); }
static __device__ __forceinline__ float bf_hi(uint32_t u) { return __uint_as_float(u & 0xffff0000u); }

// ---------------- count + W-pack (fused, independent work) ----------------
// pack layout: frag f = kstep*8 + tile (0..31); element ((f*64)+lane)*8 + j
// maps to W[k = kstep*32 + (lane>>4)*8 + j][nn = tile*16 + (lane&15)]

__global__ void countpack_kernel(const int* __restrict__ col, int* __restrict__ cnt, int E,
                                 const float* __restrict__ W1, const float* __restrict__ W2,
                                 uint16_t* __restrict__ Wh, uint16_t* __restrict__ Wl) {
    int tid = blockIdx.x * blockDim.x + threadIdx.x;
    if (tid < 2 * 16384) {
        int layer = tid >> 14;
        int li = tid & 16383;
        int j = li & 7, lane = (li >> 3) & 63, f = li >> 9;
        int kstep = f >> 3, tile = f & 7;
        int k = kstep * 32 + ((lane >> 4) * 8) + j;
        int nn = tile * 16 + (lane & 15);
        const float* W = layer ? W2 : W1;
        float v = W[k * 128 + nn];
        uint16_t h = f2bf(v);
        Wh[tid] = h;
        Wl[tid] = f2bf(v - bf2f(h));
    }
    if (tid < E) atomicAdd(&cnt[col[tid]], 1);
}

// ---------------- scan phase A: per-chunk sums (+ fused dinv) ----------------

__global__ __launch_bounds__(256) void scanA_kernel(const int* __restrict__ cnt,
                                                    int* __restrict__ bsum,
                                                    float* __restrict__ dinv, int n) {
    __shared__ int wsum[4];
    int b = blockIdx.x, t = threadIdx.x;
    int base = b * SCAN_CHUNK;
    int s = 0;
#pragma unroll
    for (int k = 0; k < SCAN_CHUNK / 256; k++) {
        int i = base + k * 256 + t;
        if (i < n) {
            int c = cnt[i];
            s += c;
            dinv[i] = rsqrtf((float)c + 1.0f);
        }
    }
#pragma unroll
    for (int off = 32; off > 0; off >>= 1) s += __shfl_xor(s, off, 64);
    if ((t & 63) == 0) wsum[t >> 6] = s;
    __syncthreads();
    if (t == 0) bsum[b] = wsum[0] + wsum[1] + wsum[2] + wsum[3];
}

// ---------------- scan phase C: local exclusive scan, block bases inlined ----------------

__global__ __launch_bounds__(256) void scanC_kernel(const int* __restrict__ cnt,
                                                    const int* __restrict__ bsum,
                                                    int* __restrict__ offs, int n, int nb) {
    __shared__ int stage[SCAN_CHUNK];
    __shared__ int res[SCAN_CHUNK];
    __shared__ int tsum[256];
    __shared__ int sb[64];
    int b = blockIdx.x, t = threadIdx.x;
    if (t < 64) {
        int v = (t < nb) ? bsum[t] : 0;
        int inc = v;
#pragma unroll
        for (int off = 1; off < 64; off <<= 1) {
            int u = __shfl_up(inc, off, 64);
            if (t >= off) inc += u;
        }
        sb[t] = inc;
    }
    int base = b * SCAN_CHUNK;
#pragma unroll
    for (int k = 0; k < SCAN_CHUNK / 256; k++) {
        int i = base + k * 256 + t;
        stage[k * 256 + t] = (i < n) ? cnt[i] : 0;
    }
    __syncthreads();
    int my = 0;
#pragma unroll
    for (int j = 0; j < 8; j++) my += stage[t * 8 + j];
    tsum[t] = my;
    __syncthreads();
    for (int off = 1; off < 256; off <<= 1) {
        int v = (t >= off) ? tsum[t - off] : 0;
        __syncthreads();
        tsum[t] += v;
        __syncthreads();
    }
    int bbase = (b == 0) ? 0 : sb[b - 1];
    int run = tsum[t] - my + bbase;
#pragma unroll
    for (int j = 0; j < 8; j++) {
        res[t * 8 + j] = run;
        run += stage[t * 8 + j];
    }
    __syncthreads();
#pragma unroll
    for (int k = 0; k < SCAN_CHUNK / 256; k++) {
        int i = base + k * 256 + t;
        if (i < n) offs[i] = res[k * 256 + t];
    }
    if (b == gridDim.x - 1 && t == 0) offs[n] = sb[nb - 1];
}

__global__ void fill_kernel(const int* row, const int* col, const int* offs,
                            int* curs, int* adj, int E) {
    int e = blockIdx.x * blockDim.x + threadIdx.x;
    if (e < E) {
        int c = col[e];
        int p = atomicAdd(&curs[c], 1);
        adj[offs[c] + p] = row[e];
    }
}

// ---------------- MFMA GEMM: xwb[i,:] = bf16( dinv[i] * (A[i,:] @ W) ) ----------------
// split-bf16 (Markidis): A = Ah + Al, W = Wh + Wl; A@W ≈ Ah@Wh + Ah@Wl + Al@Wh

__global__ __launch_bounds__(256) void gemm_mfma_kernel(const float* __restrict__ A,
                                                        const uint16_t* __restrict__ Wph,
                                                        const uint16_t* __restrict__ Wpl,
                                                        const float* __restrict__ dinv,
                                                        uint16_t* __restrict__ Cb, int M) {
    __shared__ uint16_t Ah[64][LDA];
    __shared__ uint16_t Al[64][LDA];
    int t = threadIdx.x;
    int base_row = blockIdx.x * 64;

#pragma unroll
    for (int kk = 0; kk < 8; kk++) {
        int idx = kk * 256 + t;
        int r = idx >> 5;
        int c4 = idx & 31;
        int gr = base_row + r;
        float4 f = (gr < M) ? *(const float4*)(A + (size_t)gr * D + c4 * 4)
                            : make_float4(0.f, 0.f, 0.f, 0.f);
        uint16_t h0 = f2bf(f.x), h1 = f2bf(f.y), h2 = f2bf(f.z), h3 = f2bf(f.w);
        uint16_t l0 = f2bf(f.x - bf2f(h0)), l1 = f2bf(f.y - bf2f(h1));
        uint16_t l2 = f2bf(f.z - bf2f(h2)), l3 = f2bf(f.w - bf2f(h3));
        *(ushort4*)&Ah[r][c4 * 4] = make_ushort4(h0, h1, h2, h3);
        *(ushort4*)&Al[r][c4 * 4] = make_ushort4(l0, l1, l2, l3);
    }
    __syncthreads();

    int lane = t & 63, w = t >> 6;
    int m_l = lane & 15, quad = lane >> 4;
    int arow = w * 16 + m_l;

    v4f acc[8];
#pragma unroll
    for (int i = 0; i < 8; i++) acc[i] = (v4f){0.f, 0.f, 0.f, 0.f};

#pragma unroll
    for (int ks = 0; ks < 4; ks++) {
        v8s ah = *(const v8s*)&Ah[arow][ks * 32 + quad * 8];
        v8s al = *(const v8s*)&Al[arow][ks * 32 + quad * 8];
#pragma unroll
        for (int ti = 0; ti < 8; ti++) {
            int f = ks * 8 + ti;
            v8s bh = *(const v8s*)(Wph + ((size_t)(f * 64 + lane)) * 8);
            v8s bl = *(const v8s*)(Wpl + ((size_t)(f * 64 + lane)) * 8);
            acc[ti] = __builtin_amdgcn_mfma_f32_16x16x32_bf16(al, bh, acc[ti], 0, 0, 0);
            acc[ti] = __builtin_amdgcn_mfma_f32_16x16x32_bf16(ah, bl, acc[ti], 0, 0, 0);
            acc[ti] = __builtin_amdgcn_mfma_f32_16x16x32_bf16(ah, bh, acc[ti], 0, 0, 0);
        }
    }

    int rbase = base_row + w * 16 + quad * 4;
#pragma unroll
    for (int reg = 0; reg < 4; reg++) {
        int gr = rbase + reg;
        if (gr < M) {
            float di = dinv[gr];
#pragma unroll
            for (int ti = 0; ti < 8; ti++) {
                Cb[(size_t)gr * D + ti * 16 + m_l] = f2bf(di * acc[ti][reg]);
            }
        }
    }
}

// ---------------- aggregation: one wave per node ----------------
// wave-uniform adj indices -> scalar loads; 8 independent row gathers in flight.

__global__ __launch_bounds__(256) void agg_kernel(const uint32_t* __restrict__ xwb,
                                                  const int* __restrict__ adj,
                                                  const int* __restrict__ offs,
                                                  const float* __restrict__ dinv,
                                                  const float* __restrict__ bias,
                                                  float* __restrict__ hout, int n) {
    int wave = (int)((blockIdx.x * (size_t)blockDim.x + threadIdx.x) >> 6);
    int lane = threadIdx.x & 63;
    if (wave >= n) return;
    int i = wave;
    uint32_t su = xwb[(size_t)i * (D / 2) + lane];
    float acc0 = bf_lo(su);
    float acc1 = bf_hi(su);
    int s = offs[i], e = offs[i + 1];
    int j = s;
    for (; j + 7 < e; j += 8) {
        int r0 = adj[j],     r1 = adj[j + 1], r2 = adj[j + 2], r3 = adj[j + 3];
        int r4 = adj[j + 4], r5 = adj[j + 5], r6 = adj[j + 6], r7 = adj[j + 7];
        uint32_t u0 = xwb[(size_t)r0 * (D / 2) + lane];
        uint32_t u1 = xwb[(size_t)r1 * (D / 2) + lane];
        uint32_t u2 = xwb[(size_t)r2 * (D / 2) + lane];
        uint32_t u3 = xwb[(size_t)r3 * (D / 2) + lane];
        uint32_t u4 = xwb[(size_t)r4 * (D / 2) + lane];
        uint32_t u5 = xwb[(size_t)r5 * (D / 2) + lane];
        uint32_t u6 = xwb[(size_t)r6 * (D / 2) + lane];
        uint32_t u7 = xwb[(size_t)r7 * (D / 2) + lane];
        acc0 += bf_lo(u0); acc1 += bf_hi(u0);
        acc0 += bf_lo(u1); acc1 += bf_hi(u1);
        acc0 += bf_lo(u2); acc1 += bf_hi(u2);
        acc0 += bf_lo(u3); acc1 += bf_hi(u3);
        acc0 += bf_lo(u4); acc1 += bf_hi(u4);
        acc0 += bf_lo(u5); acc1 += bf_hi(u5);
        acc0 += bf_lo(u6); acc1 += bf_hi(u6);
        acc0 += bf_lo(u7); acc1 += bf_hi(u7);
    }
    for (; j + 3 < e; j += 4) {
        int r0 = adj[j], r1 = adj[j + 1], r2 = adj[j + 2], r3 = adj[j + 3];
        uint32_t u0 = xwb[(size_t)r0 * (D / 2) + lane];
        uint32_t u1 = xwb[(size_t)r1 * (D / 2) + lane];
        uint32_t u2 = xwb[(size_t)r2 * (D / 2) + lane];
        uint32_t u3 = xwb[(size_t)r3 * (D / 2) + lane];
        acc0 += bf_lo(u0); acc1 += bf_hi(u0);
        acc0 += bf_lo(u1); acc1 += bf_hi(u1);
        acc0 += bf_lo(u2); acc1 += bf_hi(u2);
        acc0 += bf_lo(u3); acc1 += bf_hi(u3);
    }
    for (; j < e; j++) {
        int r = adj[j];
        uint32_t u = xwb[(size_t)r * (D / 2) + lane];
        acc0 += bf_lo(u); acc1 += bf_hi(u);
    }
    float di = dinv[i];
    float2 bv = ((const float2*)bias)[lane];
    float o0 = fmaxf(fmaf(di, acc0, bv.x), 0.f);
    float o1 = fmaxf(fmaf(di, acc1, bv.y), 0.f);
    ((float2*)(hout + (size_t)i * D))[lane] = make_float2(o0, o1);
}

// ---------------- edge-classifier precompute ----------------

__global__ __launch_bounds__(256) void pq_kernel(const float* __restrict__ h,
                                                 const float* __restrict__ Wfc,
                                                 const float* __restrict__ bfc,
                                                 float* __restrict__ P1,
                                                 float* __restrict__ P2, int n) {
    int i = blockIdx.x * blockDim.x + threadIdx.x;
    if (i >= n) return;
    const float4* hr = (const float4*)(h + (size_t)i * D);
    const float4* W4 = (const float4*)Wfc;
    float p0 = bfc[0], p1 = bfc[1], p2 = bfc[2], p3 = bfc[3];
    float q0 = 0.f, q1 = 0.f, q2 = 0.f, q3 = 0.f;
#pragma unroll 8
    for (int kk = 0; kk < 32; kk++) {
        float4 f = hr[kk];
#pragma unroll
        for (int j = 0; j < 4; j++) {
            float fv = (j == 0) ? f.x : (j == 1) ? f.y : (j == 2) ? f.z : f.w;
            int k = kk * 4 + j;
            float4 w1 = W4[k];
            float4 w2 = W4[128 + k];
            p0 = fmaf(fv, w1.x, p0); p1 = fmaf(fv, w1.y, p1);
            p2 = fmaf(fv, w1.z, p2); p3 = fmaf(fv, w1.w, p3);
            q0 = fmaf(fv, w2.x, q0); q1 = fmaf(fv, w2.y, q1);
            q2 = fmaf(fv, w2.z, q2); q3 = fmaf(fv, w2.w, q3);
        }
    }
    ((float4*)P1)[i] = make_float4(p0, p1, p2, p3);
    ((float4*)P2)[i] = make_float4(q0, q1, q2, q3);
}

// ---------------- edge classifier: one THREAD per edge ----------------

__global__ __launch_bounds__(256) void edge2_kernel(const int* __restrict__ row,
                                                    const int* __restrict__ col,
                                                    const float* __restrict__ P1,
                                                    const float* __restrict__ P2,
                                                    float* __restrict__ out, int E) {
    int e = blockIdx.x * blockDim.x + threadIdx.x;
    if (e >= E) return;
    int r = row[e], c = col[e];
    float4 a = ((const float4*)P1)[r];
    float4 b = ((const float4*)P2)[c];
    float sx = a.x + b.x, sy = a.y + b.y, sz = a.z + b.z, sw = a.w + b.w;
    float m = fmaxf(fmaxf(sx, sy), fmaxf(sz, sw));
    float e0 = expf(sx - m), e1 = expf(sy - m), e2 = expf(sz - m), e3 = expf(sw - m);
    float lse = m + logf(e0 + e1 + e2 + e3);
    *(float4*)(out + (size_t)e * 4) = make_float4(sx - lse, sy - lse, sz - lse, sw - lse);
}

// ---------------- launch ----------------

extern "C" void kernel_launch(void* const* d_in, const int* in_sizes, int n_in,
                              void* d_out, int out_size, void* d_ws, size_t ws_size,
                              hipStream_t stream) {
    const float* x   = (const float*)d_in[0];
    const int*   ei  = (const int*)d_in[1];
    const float* W1  = (const float*)d_in[2];
    const float* b1  = (const float*)d_in[3];
    const float* W2  = (const float*)d_in[4];
    const float* b2  = (const float*)d_in[5];
    const float* Wfc = (const float*)d_in[6];
    const float* bfc = (const float*)d_in[7];
    float* out = (float*)d_out;

    int n = in_sizes[0] / D;        // 50000
    int E = in_sizes[1] / 2;        // 600000
    const int* row = ei;            // edge_index[0]
    const int* col = ei + E;        // edge_index[1]

    int nbScan = (n + SCAN_CHUNK - 1) / SCAN_CHUNK;   // 25

    // workspace layout (all segments 16B-aligned)
    uint16_t* xwb  = (uint16_t*)d_ws;                    // n*D bf16 (dinv-prescaled xW)
    float*    h    = (float*)(xwb + (size_t)n * D);      // n*D f32 (layer-1 output only)
    int*      cnt  = (int*)(h + (size_t)n * D);          // n   } adjacent for one memset
    int*      curs = cnt + n;                            // n   }
    int*      offs = curs + n;                           // n+4 (padded for alignment)
    int*      bsum = offs + (n + 4);                     // 64
    int*      adj  = bsum + 64;                          // E
    float*    dinv = (float*)(adj + E);                  // n
    uint16_t* Wph  = (uint16_t*)(dinv + n);              // 2*16384 (layer-major)
    uint16_t* Wpl  = Wph + 2 * 16384;                    // 2*16384
    float*    P1   = (float*)(Wpl + 2 * 16384);          // n*4
    float*    P2   = P1 + (size_t)n * 4;                 // n*4

    int nb_n = (n + 255) / 256;
    int nb_e = (E + 255) / 256;

    // CSR build (+ W pack fused into count)
    hipMemsetAsync(cnt, 0, (size_t)2 * n * sizeof(int), stream);   // cnt + curs
    countpack_kernel<<<nb_e, 256, 0, stream>>>(col, cnt, E, W1, W2, Wph, Wpl);
    scanA_kernel<<<nbScan, 256, 0, stream>>>(cnt, bsum, dinv, n);
    scanC_kernel<<<nbScan, 256, 0, stream>>>(cnt, bsum, offs, n, nbScan);
    fill_kernel<<<nb_e, 256, 0, stream>>>(row, col, offs, curs, adj, E);

    int nbG = (n + 63) / 64;

    // layer 1
    gemm_mfma_kernel<<<nbG, 256, 0, stream>>>(x, Wph, Wpl, dinv, xwb, n);
    agg_kernel<<<(n + 3) / 4, 256, 0, stream>>>((const uint32_t*)xwb, adj, offs, dinv, b1, h, n);
    // layer 2
    gemm_mfma_kernel<<<nbG, 256, 0, stream>>>(h, Wph + 16384, Wpl + 16384, dinv, xwb, n);
    agg_kernel<<<(n + 3) / 4, 256, 0, stream>>>((const uint32_t*)xwb, adj, offs, dinv, b2, h, n);

    // edge classifier
    pq_kernel<<<nb_n, 256, 0, stream>>>(h, Wfc, bfc, P1, P2, n);
    edge2_kernel<<<nb_e, 256, 0, stream>>>(row, col, P1, P2, out, E);
}